// Round 14
// baseline (6011.063 us; speedup 1.0000x reference)
//
#include <hip/hip_runtime.h>
#include <cstdint>
#include <cstddef>

#define DEV __device__ __forceinline__

typedef __attribute__((ext_vector_type(8))) __bf16 bf16x8;
typedef __attribute__((ext_vector_type(4))) float f32x4;

// ---------------- problem constants ----------------
// B=2 T=16 L=256 IN=768 D=1024 H=16 HD=64 S=262 P=6 HID=4096 DEPTH=8
#define NTOK   8384            // B*T*S
#define NTOKP  8448            // padded to 66*128 (= 33*256)
#define NLAT   8192            // B*T*L

DEV float b2f(unsigned short u) {
  unsigned int x = ((unsigned int)u) << 16;
  return __builtin_bit_cast(float, x);
}
DEV unsigned short f2b(float f) {
  unsigned int x = __builtin_bit_cast(unsigned int, f);
  x += 0x7fffu + ((x >> 16) & 1u);
  return (unsigned short)(x >> 16);
}
DEV float wred_sum(float v) {
#pragma unroll
  for (int o = 32; o; o >>= 1) v += __shfl_xor(v, o);
  return v;
}
DEV bool mask_or(const void* p, int i) {
  return ((const unsigned char*)p)[i] != 0 || ((const int*)p)[i] != 0;
}
DEV bool mask_and(const void* p, int i) {
  return ((const unsigned char*)p)[i] != 0 && ((const int*)p)[i] != 0;
}
// raw workgroup barrier (NO vmcnt/lgkm drain) + compiler memory fences
DEV void wgb() {
  asm volatile("" ::: "memory");
  __builtin_amdgcn_s_barrier();
  asm volatile("" ::: "memory");
}

// ---------------- elementwise / setup kernels ----------------

__global__ void conv_f2b(const float* __restrict__ in, unsigned short* __restrict__ out, int n4) {
  int i = blockIdx.x * 256 + threadIdx.x;
  if (i < n4) {
    float4 v = ((const float4*)in)[i];
    ushort4 o;
    o.x = f2b(v.x); o.y = f2b(v.y); o.z = f2b(v.z); o.w = f2b(v.w);
    ((ushort4*)out)[i] = o;
  }
}

__global__ void build_rope(float2* __restrict__ out, int npos) {
  int idx = blockIdx.x * 256 + threadIdx.x;
  if (idx >= npos * 32) return;
  int pos = idx >> 5, i = idx & 31;
  float inv = powf(1000.0f, -(float)(2 * i) * (1.0f / 64.0f));
  float ang = (float)pos * inv;
  float sv, cv;
  sincosf(ang, &sv, &cv);
  out[idx] = make_float2(cv, sv);
}

// fp32 [K][N] -> bf16 [row(n)][K] ; MODE 0: row=n
// MODE 1 (W1 16-col interleave): row = ((n>>4)<<5) | (n&15)
// MODE 2 (W2):                    row = (((n>>4)<<5) + 16) | (n&15)
__global__ __launch_bounds__(256) void transpose_w(const float* __restrict__ in,
                                                   unsigned short* __restrict__ out,
                                                   int K, int N, int ostride, int mode) {
  __shared__ float tile[32][33];
  int kb = blockIdx.x * 32, nb = blockIdx.y * 32;
  int tx = threadIdx.x & 31, ty = threadIdx.x >> 5; // 32x8
#pragma unroll
  for (int i = 0; i < 32; i += 8)
    tile[ty + i][tx] = in[(size_t)(kb + ty + i) * N + (nb + tx)];
  __syncthreads();
#pragma unroll
  for (int i = 0; i < 32; i += 8) {
    int n = nb + ty + i;
    int row = n;
    if (mode == 1) row = ((n >> 4) << 5) | (n & 15);
    else if (mode == 2) row = (((n >> 4) << 5) + 16) | (n & 15);
    out[(size_t)row * ostride + (kb + tx)] = f2b(tile[tx][ty + i]);
  }
}

// h1 = silu(nl*w1+b1) ; nz = b2 (init for noise_mm accumulate). 128 blocks x 256.
__global__ __launch_bounds__(256) void noise_h1(const float* __restrict__ nlvl,
                                                const float* __restrict__ w1,
                                                const float* __restrict__ b1,
                                                const float* __restrict__ b2,
                                                float* __restrict__ h1,
                                                float* __restrict__ nz) {
  int i = blockIdx.x * 256 + threadIdx.x; // 32*1024
  int bt = i >> 10, d = i & 1023;
  float v = nlvl[bt] * w1[d] + b1[d];
  h1[i] = v / (1.0f + expf(-v));
  nz[i] = b2[d];
}

// nz += h1[32,1024] @ w2[1024,1024]
__global__ __launch_bounds__(256) void noise_mm(const float* __restrict__ h1,
                                                const float* __restrict__ w2,
                                                float* __restrict__ nz) {
  __shared__ float hs[32][128];
  int kc = blockIdx.x >> 4, dpg = blockIdx.x & 15;
  int tid = threadIdx.x;
  int k0 = kc * 128;
  for (int idx = tid; idx < 32 * 128; idx += 256) {
    int bt = idx >> 7, k = idx & 127;
    hs[bt][k] = h1[bt * 1024 + k0 + k];
  }
  __syncthreads();
  int dp = dpg * 64 + (tid & 63);
  int bt0 = (tid >> 6) * 8;
  float acc[8] = {};
  for (int k = 0; k < 128; ++k) {
    float w = w2[(size_t)(k0 + k) * 1024 + dp];
#pragma unroll
    for (int j = 0; j < 8; ++j) acc[j] += hs[bt0 + j][k] * w;
  }
#pragma unroll
  for (int j = 0; j < 8; ++j) atomicAdd(&nz[(bt0 + j) * 1024 + dp], acc[j]);
}

// writes x rows 0..5 per frame (registers, noise, action)
__global__ void embed_special(float* __restrict__ x, const float* __restrict__ regs,
                              const float* __restrict__ nz, const float* __restrict__ base_emb,
                              const float* __restrict__ actions, const float* __restrict__ action_w,
                              const float* __restrict__ action_b,
                              const void* __restrict__ amask) {
  int bt = blockIdx.x, d = threadIdx.x; // 32 blocks x 1024 threads
  float* xr = x + (size_t)bt * 262 * 1024;
#pragma unroll
  for (int r = 0; r < 4; ++r) xr[r * 1024 + d] = regs[r * 1024 + d];
  xr[4 * 1024 + d] = nz[(size_t)bt * 1024 + d];
  float a = base_emb[d];
  if (mask_or(amask, bt)) {
    float s = action_b[d];
#pragma unroll
    for (int i = 0; i < 6; ++i) s += actions[bt * 6 + i] * action_w[i * 1024 + d];
    a += s;
  }
  xr[5 * 1024 + d] = a;
}

// RMS over D=1024 with weight; REMAP compacts latent tokens (for final norm)
template <bool REMAP>
__global__ __launch_bounds__(256) void rms_k(const float* __restrict__ x,
                                             const float* __restrict__ w,
                                             unsigned short* __restrict__ out) {
  int m = blockIdx.x, tid = threadIdx.x;
  size_t src = REMAP ? ((size_t)(m >> 8) * 262 + 6 + (m & 255)) : (size_t)m;
  float4 v = ((const float4*)(x + src * 1024))[tid];
  float ss = v.x * v.x + v.y * v.y + v.z * v.z + v.w * v.w;
  ss = wred_sum(ss);
  __shared__ float sred[4];
  if ((tid & 63) == 0) sred[tid >> 6] = ss;
  __syncthreads();
  float tot = sred[0] + sred[1] + sred[2] + sred[3];
  float sc = rsqrtf(tot * (1.0f / 1024.0f) + 1e-6f);
  float4 wv = ((const float4*)w)[tid];
  ushort4 o;
  o.x = f2b(v.x * sc * wv.x); o.y = f2b(v.y * sc * wv.y);
  o.z = f2b(v.z * sc * wv.z); o.w = f2b(v.w * sc * wv.w);
  ((ushort4*)(out + (size_t)m * 1024))[tid] = o;
}

// ---------------- attention ----------------
#define KSTR 72
#define VSTR 296
__global__ __launch_bounds__(256) void attn_spatial(const unsigned short* __restrict__ qkv,
                                                    unsigned short* __restrict__ o,
                                                    const float2* __restrict__ rope) {
  __shared__ unsigned short Ks[272 * KSTR];
  __shared__ unsigned short Vt[64 * VSTR];
  __shared__ unsigned short Ps[4][16 * VSTR];
  const int h = blockIdx.x & 15;
  const int bt = blockIdx.x >> 4;
  const int tid = threadIdx.x, wave = tid >> 6, lane = tid & 63;
  const size_t tb = (size_t)bt * 262;

  {
    const int d = lane;
#pragma unroll 1
    for (int pss = 0; pss < 17; ++pss) {
      const int t0 = (pss * 4 + wave) * 4;
      ushort4 vp;
      unsigned short* vpp = (unsigned short*)&vp;
#pragma unroll
      for (int j = 0; j < 4; ++j) {
        const int t = t0 + j;
        float kv = 0.f, vv = 0.f;
        if (t < 262) {
          const size_t rb = (tb + t) * 3072 + h * 64 + d;
          kv = b2f(qkv[rb + 1024]);
          vv = b2f(qkv[rb + 2048]);
        }
        float ss = wred_sum(kv * kv);
        kv *= rsqrtf(ss * (1.0f / 64.0f) + 1e-6f);
        float partner = __shfl_xor(kv, 1);
        const int tc = t < 262 ? t : 261;
        float2 cs = rope[tc * 32 + (d >> 1)];
        kv = ((d & 1) == 0) ? (kv * cs.x - partner * cs.y)
                            : (partner * cs.y + kv * cs.x);
        Ks[t * KSTR + d] = f2b(kv);
        vpp[j] = f2b(vv);
      }
      *(ushort4*)(&Vt[d * VSTR + t0]) = vp;
    }
    for (int idx = tid; idx < 64 * 24; idx += 256) {
      Vt[(idx / 24) * VSTR + 272 + (idx % 24)] = 0;
    }
    for (int idx = tid; idx < 4 * 16 * 34; idx += 256) {
      int w = idx / (16 * 34), r = (idx / 34) & 15, c = idx % 34;
      Ps[w][r * VSTR + 262 + c] = 0;
    }
  }
  __syncthreads();

  unsigned short* Pw = &Ps[wave][0];
  const int kcol = lane & 15;
  const int g8 = (lane >> 4) << 3;
  const int g4 = g8 >> 1;
  const int rq = (lane >> 4) << 2;

#pragma unroll 1
  for (int qc = wave; qc < 17; qc += 4) {
    const int q0 = qc * 16;
    const int qrow = q0 + kcol;
    const int grow = qrow < 262 ? qrow : 261;
    const unsigned short* qp = qkv + (tb + grow) * 3072 + h * 64 + g8;
    float qv[16];
    {
      ushort4 a = *(const ushort4*)qp, b = *(const ushort4*)(qp + 4);
      ushort4 c = *(const ushort4*)(qp + 32), e = *(const ushort4*)(qp + 36);
      qv[0] = b2f(a.x); qv[1] = b2f(a.y); qv[2] = b2f(a.z); qv[3] = b2f(a.w);
      qv[4] = b2f(b.x); qv[5] = b2f(b.y); qv[6] = b2f(b.z); qv[7] = b2f(b.w);
      qv[8] = b2f(c.x); qv[9] = b2f(c.y); qv[10] = b2f(c.z); qv[11] = b2f(c.w);
      qv[12] = b2f(e.x); qv[13] = b2f(e.y); qv[14] = b2f(e.z); qv[15] = b2f(e.w);
    }
    float ss = 0.f;
#pragma unroll
    for (int i = 0; i < 16; ++i) ss += qv[i] * qv[i];
    ss += __shfl_xor(ss, 16);
    ss += __shfl_xor(ss, 32);
    const float qsc = rsqrtf(ss * (1.0f / 64.0f) + 1e-6f);
    bf16x8 aq0, aq1;
    unsigned short* u0 = (unsigned short*)&aq0;
    unsigned short* u1 = (unsigned short*)&aq1;
#pragma unroll
    for (int i = 0; i < 4; ++i) {
      float2 cs0 = rope[grow * 32 + g4 + i];
      float a = qv[2 * i] * qsc, b = qv[2 * i + 1] * qsc;
      u0[2 * i] = f2b(a * cs0.x - b * cs0.y);
      u0[2 * i + 1] = f2b(a * cs0.y + b * cs0.x);
      float2 cs1 = rope[grow * 32 + 16 + g4 + i];
      float a1 = qv[8 + 2 * i] * qsc, b1 = qv[9 + 2 * i] * qsc;
      u1[2 * i] = f2b(a1 * cs1.x - b1 * cs1.y);
      u1[2 * i + 1] = f2b(a1 * cs1.y + b1 * cs1.x);
    }
    f32x4 sc[17];
#pragma unroll
    for (int kc = 0; kc < 17; ++kc) {
      const unsigned short* kb = &Ks[(kc * 16 + kcol) * KSTR + g8];
      f32x4 z = {};
      z = __builtin_amdgcn_mfma_f32_16x16x32_bf16(aq0, *(const bf16x8*)kb, z, 0, 0, 0);
      sc[kc] = __builtin_amdgcn_mfma_f32_16x16x32_bf16(aq1, *(const bf16x8*)(kb + 32), z, 0, 0, 0);
    }
#pragma unroll
    for (int kc = 0; kc < 17; ++kc) {
      const int k = kc * 16 + kcol;
#pragma unroll
      for (int j = 0; j < 4; ++j) {
        const int sq = q0 + rq + j;
        const bool valid = (k < 262) && ((sq != 4 && sq != 5) || (k == sq));
        sc[kc][j] = valid ? sc[kc][j] * 0.125f : -1e30f;
      }
    }
    float sm[4];
#pragma unroll
    for (int j = 0; j < 4; ++j) {
      float m = -1e30f;
#pragma unroll
      for (int kc = 0; kc < 17; ++kc) m = fmaxf(m, sc[kc][j]);
#pragma unroll
      for (int off = 1; off < 16; off <<= 1) m = fmaxf(m, __shfl_xor(m, off));
      float s = 0.f;
#pragma unroll
      for (int kc = 0; kc < 17; ++kc) {
        float e = expf(sc[kc][j] - m);
        sc[kc][j] = e;
        s += e;
      }
#pragma unroll
      for (int off = 1; off < 16; off <<= 1) s += __shfl_xor(s, off);
      sm[j] = 1.0f / s;
    }
#pragma unroll
    for (int kc = 0; kc < 17; ++kc) {
      const int k = kc * 16 + kcol;
#pragma unroll
      for (int j = 0; j < 4; ++j)
        Pw[(rq + j) * VSTR + k] = f2b(sc[kc][j] * sm[j]);
    }
    f32x4 oacc[4] = {};
#pragma unroll
    for (int tc = 0; tc < 9; ++tc) {
      const bf16x8 ap = *(const bf16x8*)(&Pw[kcol * VSTR + tc * 32 + g8]);
#pragma unroll
      for (int nt = 0; nt < 4; ++nt) {
        const bf16x8 bv = *(const bf16x8*)(&Vt[(nt * 16 + kcol) * VSTR + tc * 32 + g8]);
        oacc[nt] = __builtin_amdgcn_mfma_f32_16x16x32_bf16(ap, bv, oacc[nt], 0, 0, 0);
      }
    }
#pragma unroll
    for (int nt = 0; nt < 4; ++nt) {
#pragma unroll
      for (int j = 0; j < 4; ++j) {
        const int sq = q0 + rq + j;
        if (sq < 262)
          o[(tb + sq) * 1024 + h * 64 + nt * 16 + kcol] = f2b(oacc[nt][j]);
      }
    }
  }
}

// temporal: one wave per (b,s,h); per-t rms+rope fused; strict-causal T=16
__global__ __launch_bounds__(256) void attn_temporal(const unsigned short* __restrict__ qkv,
                                                     unsigned short* __restrict__ o,
                                                     const float2* __restrict__ rope,
                                                     const void* __restrict__ indep) {
  int gw = blockIdx.x * 4 + (threadIdx.x >> 6);
  int lane = threadIdx.x & 63;
  if (gw >= NTOK) return;
  int h = gw & 15;
  int s = (gw >> 4) % 262;
  int b = (gw >> 4) / 262;
  bool dead = (s < 6) || mask_and(indep, b);
  float q[16], kk[16], vv[16], out[16];
#pragma unroll
  for (int t = 0; t < 16; ++t) {
    out[t] = 0.f;
    if (!dead) {
      size_t off = ((size_t)((b * 16 + t) * 262 + s)) * 3072 + h * 64 + lane;
      q[t] = b2f(qkv[off]);
      kk[t] = b2f(qkv[off + 1024]);
      vv[t] = b2f(qkv[off + 2048]);
    }
  }
  if (!dead) {
#pragma unroll
    for (int t = 0; t < 16; ++t) {
      float sq_ = wred_sum(q[t] * q[t]);
      float qv = q[t] * rsqrtf(sq_ * (1.0f / 64.0f) + 1e-6f);
      float sk_ = wred_sum(kk[t] * kk[t]);
      float kv = kk[t] * rsqrtf(sk_ * (1.0f / 64.0f) + 1e-6f);
      float2 cs = rope[t * 32 + (lane >> 1)];
      float qp = __shfl_xor(qv, 1);
      float kp = __shfl_xor(kv, 1);
      q[t] = ((lane & 1) == 0) ? (qv * cs.x - qp * cs.y) : (qp * cs.y + qv * cs.x);
      kk[t] = ((lane & 1) == 0) ? (kv * cs.x - kp * cs.y) : (kp * cs.y + kv * cs.x);
    }
#pragma unroll
    for (int t = 1; t < 16; ++t) {
      float m = -1e30f, l = 0.f, acc = 0.f;
#pragma unroll
      for (int j = 0; j < t; ++j) {
        float pr = q[t] * kk[j];
#pragma unroll
        for (int o2 = 32; o2; o2 >>= 1) pr += __shfl_xor(pr, o2);
        pr *= 0.125f;
        float mn = fmaxf(m, pr);
        float cor = expf(m - mn);
        float e = expf(pr - mn);
        l = l * cor + e;
        acc = acc * cor + e * vv[j];
        m = mn;
      }
      out[t] = acc / l;
    }
  }
#pragma unroll
  for (int t = 0; t < 16; ++t) {
    size_t off = ((size_t)((b * 16 + t) * 262 + s)) * 1024 + h * 64 + lane;
    o[off] = f2b(out[t]);
  }
}

// ---------------- GEMM 128x128 (round-4 structure: proven plateau) ----------------
DEV void stage_tiles(const unsigned short* __restrict__ A, const unsigned short* __restrict__ Bw,
                     size_t arow0, size_t brow0, int lda, int k0,
                     unsigned short* As, unsigned short* Bs, int wave, int lane) {
  const int srow = lane >> 2;
  const int scol = (lane & 3) * 8;
#pragma unroll
  for (int c = 0; c < 2; ++c) {
    const int chunk = wave * 2 + c;
    unsigned short* ga = const_cast<unsigned short*>(A + (arow0 + chunk * 16 + srow) * lda + k0 + scol);
    unsigned short* gb = const_cast<unsigned short*>(Bw + (brow0 + chunk * 16 + srow) * lda + k0 + scol);
    __builtin_amdgcn_global_load_lds((__attribute__((address_space(1))) void*)ga,
                                     (__attribute__((address_space(3))) void*)(As + chunk * 512),
                                     16, 0, 0);
    __builtin_amdgcn_global_load_lds((__attribute__((address_space(1))) void*)gb,
                                     (__attribute__((address_space(3))) void*)(Bs + chunk * 512),
                                     16, 0, 0);
  }
}

template <int EPI>
__global__ __launch_bounds__(256) void gemm_k(const unsigned short* __restrict__ A,
                                              const unsigned short* __restrict__ Bw,
                                              void* __restrict__ C,
                                              const float* __restrict__ aux,
                                              int Mvalid, int K, int lda, int ldc) {
  __shared__ unsigned short As[2][128 * 32];
  __shared__ unsigned short Bs[2][128 * 32];
  const int tid = threadIdx.x;
  const int wave = tid >> 6, lane = tid & 63;
  const int wm = wave >> 1, wn = wave & 1;
  const size_t arow0 = (size_t)blockIdx.x * 128;
  const size_t brow0 = (size_t)blockIdx.y * 128;

  f32x4 acc[4][4] = {};
  const int KT = K >> 5;

  stage_tiles(A, Bw, arow0, brow0, lda, 0, As[0], Bs[0], wave, lane);
  __syncthreads();
  int buf = 0;
  for (int kt = 0; kt < KT; ++kt) {
    if (kt + 1 < KT)
      stage_tiles(A, Bw, arow0, brow0, lda, (kt + 1) << 5, As[buf ^ 1], Bs[buf ^ 1], wave, lane);
    const int kk = (lane >> 4) * 8;
    const int rsel = lane & 15;
    bf16x8 af[4], bfr[4];
#pragma unroll
    for (int mt = 0; mt < 4; ++mt)
      af[mt] = *reinterpret_cast<const bf16x8*>(&As[buf][(wm * 64 + mt * 16 + rsel) * 32 + kk]);
#pragma unroll
    for (int nt = 0; nt < 4; ++nt)
      bfr[nt] = *reinterpret_cast<const bf16x8*>(&Bs[buf][(wn * 64 + nt * 16 + rsel) * 32 + kk]);
#pragma unroll
    for (int mt = 0; mt < 4; ++mt) {
#pragma unroll
      for (int nt = 0; nt < 4; ++nt)
        acc[mt][nt] = __builtin_amdgcn_mfma_f32_16x16x32_bf16(af[mt], bfr[nt], acc[mt][nt], 0, 0, 0);
    }
    __syncthreads();
    buf ^= 1;
  }

  const int rsel = lane & 15;
  const int row_base = blockIdx.x * 128 + wm * 64;
  const int col_base = blockIdx.y * 128 + wn * 64;

#pragma unroll
  for (int mt = 0; mt < 4; ++mt) {
#pragma unroll
    for (int nt = 0; nt < 4; ++nt) {
      const int col = col_base + nt * 16 + rsel;
      const int r0 = row_base + mt * 16 + ((lane >> 4) << 2);
#pragma unroll
      for (int j = 0; j < 4; ++j) {
        const int row = r0 + j;
        float v = acc[mt][nt][j];
        if (row < Mvalid) {
          if (EPI == 0) {
            ((unsigned short*)C)[(size_t)row * ldc + col] = f2b(v);
          } else if (EPI == 1) {
            float* p = (float*)C + (size_t)row * ldc + col;
            *p += v;
          } else if (EPI == 3) {
            ((float*)C)[(size_t)row * ldc + col] = v + aux[col];
          } else if (EPI == 5) {
            int xr = (row >> 8) * 262 + 6 + (row & 255);
            ((float*)C)[(size_t)xr * ldc + col] = v;
          }
        }
      }
    }
  }
}

// ---------------- GEMM 256x256, BK=64, 8-phase derived-waits (SwiGLU) --------
// 8 waves (wm=wid>>2 in 0..1, wn=wid&3), 512 thr. LDS 128KB: As[2],Bs[2] of
// 256x64 bf16 (32KB); K-tile kt -> buf kt&1. st_16x32 swizzle: phys byte =
// l ^ (((l>>9)&1)<<5) (involution) on ds_read addr; inverse on the GLOBAL
// source of linear global_load_lds writes.
// Iteration = 2 K-tiles (kt0 even, kt1=kt0+1), 8 phases, 16 MFMA each
// (2mt x 4nt x 2ks). B-frags read ONCE per K-tile (first phase) into regs ->
// B-buffer free after that phase; A-buffer free after the tile's 4th phase.
// Issue slots (1 half-tile = 2 gload_lds per phase):
//   p1:A(kt1)h0  p2:A(kt1)h1  p3:B(kt0+2)h0  p4:B(kt0+2)h1
//   p5:A(kt0+2)h0 p6:A(kt0+2)h1 p7:B(kt0+3)h0 p8:B(kt0+3)h1
// Hazard proof: each write targets a buffer whose previous content was fully
// consumed at an earlier phase barrier of the same/previous iteration.
// Counted waits (end of p4 and p8 only): vmcnt(4) allows exactly the 2 newest
// half-tiles in flight; guarantees A(kt1) [p1,p2] before p5 and A/B(kt0+2)
// [p3..p6] before next p1. Last iteration: vmcnt(0) at p4, none at p8.
DEV void stage_half(const unsigned short* __restrict__ G, size_t row0, int lda,
                    int kt, unsigned short* buf, int half, int tid) {
#pragma unroll
  for (int i = 0; i < 2; ++i) {
    const int p = half * 16384 + i * 8192 + tid * 16;   // linear LDS byte (0..32767)
    const int l = p ^ (((p >> 9) & 1) << 5);            // logical byte (involution)
    const int grow = l >> 7;                            // tile row 0..255
    const int gcol = (l & 127) >> 1;                    // col element 0..63
    unsigned short* g = const_cast<unsigned short*>(G + (row0 + grow) * (size_t)lda + kt * 64 + gcol);
    __builtin_amdgcn_global_load_lds((__attribute__((address_space(1))) void*)g,
                                     (__attribute__((address_space(3))) void*)(buf + (p >> 1)),
                                     16, 0, 0);
  }
}
DEV bf16x8 rdfrag(const unsigned short* buf, int row, int kbyte) {
  const int l = row * 128 + kbyte;
  const int ph = l ^ (((l >> 9) & 1) << 5);
  return *(const bf16x8*)((const char*)buf + ph);
}

#define PHASE8(as_, bs_, mtp, LOADB, SLOT, ENDW)                                  \
  {                                                                               \
    bf16x8 af[2][2];                                                              \
    if (LOADB) {                                                                  \
      _Pragma("unroll") for (int nt = 0; nt < 4; ++nt) {                          \
        _Pragma("unroll") for (int ks = 0; ks < 2; ++ks)                          \
          bfr[nt][ks] = rdfrag(bs_, wn * 64 + nt * 16 + rsel, ks * 64 + kb16);    \
      }                                                                           \
    }                                                                             \
    _Pragma("unroll") for (int m = 0; m < 2; ++m) {                               \
      _Pragma("unroll") for (int ks = 0; ks < 2; ++ks)                            \
        af[m][ks] = rdfrag(as_, wm * 128 + ((mtp)*2 + m) * 16 + rsel, ks * 64 + kb16); \
    }                                                                             \
    SLOT;                                                                         \
    wgb();                                                                        \
    asm volatile("s_waitcnt lgkmcnt(0)" ::: "memory");                            \
    __builtin_amdgcn_sched_barrier(0);                                            \
    __builtin_amdgcn_s_setprio(1);                                                \
    _Pragma("unroll") for (int m = 0; m < 2; ++m) {                               \
      _Pragma("unroll") for (int nt = 0; nt < 4; ++nt) {                          \
        _Pragma("unroll") for (int ks = 0; ks < 2; ++ks)                          \
          acc[(mtp)*2 + m][nt] = __builtin_amdgcn_mfma_f32_16x16x32_bf16(         \
              af[m][ks], bfr[nt][ks], acc[(mtp)*2 + m][nt], 0, 0, 0);             \
      }                                                                           \
    }                                                                             \
    __builtin_amdgcn_s_setprio(0);                                                \
    ENDW;                                                                         \
    wgb();                                                                        \
  }

// EPI 2: swiglu with W12T 16-col interleave (8192 rows) -> bf16 C[row][col/2]
template <int EPI>
__global__ __launch_bounds__(512) void gemm8p_k(const unsigned short* __restrict__ A,
                                                const unsigned short* __restrict__ Bw,
                                                void* __restrict__ C,
                                                int Mvalid, int K, int lda, int ldc) {
  __shared__ unsigned short As[2][16384];
  __shared__ unsigned short Bs[2][16384];
  const int tid = threadIdx.x;
  const int lane = tid & 63, wid = tid >> 6;
  const int wm = wid >> 2, wn = wid & 3;
  const int rsel = lane & 15;
  const int kb16 = (lane >> 4) * 16;               // k-slice byte offset within 64B half
  const size_t arow0 = (size_t)blockIdx.x * 256;
  const size_t brow0 = (size_t)blockIdx.y * 256;
  const int NT = K >> 6;                           // K-tiles of 64 (even)
  const int NITER = NT >> 1;

  f32x4 acc[8][4] = {};

  // prologue: A(0), B(0), B(1)
  stage_half(A, arow0, lda, 0, As[0], 0, tid);
  stage_half(A, arow0, lda, 0, As[0], 1, tid);
  stage_half(Bw, brow0, lda, 0, Bs[0], 0, tid);
  stage_half(Bw, brow0, lda, 0, Bs[0], 1, tid);
  stage_half(Bw, brow0, lda, 1, Bs[1], 0, tid);
  stage_half(Bw, brow0, lda, 1, Bs[1], 1, tid);
  asm volatile("s_waitcnt vmcnt(4)" ::: "memory"); // A(0),B(0) landed; B(1) in flight
  wgb();

#pragma unroll 1
  for (int it = 0; it < NITER; ++it) {
    const int kt0 = it * 2;
    const bool pf2 = (kt0 + 2) < NT;
    const bool pf3 = (kt0 + 3) < NT;
    bf16x8 bfr[4][2];
    // ---- K-tile kt0 (As[0]/Bs[0]) : phases 1-4 ----
    PHASE8(As[0], Bs[0], 0, true,
           { stage_half(A, arow0, lda, kt0 + 1, As[1], 0, tid); }, {});
    PHASE8(As[0], Bs[0], 1, false,
           { stage_half(A, arow0, lda, kt0 + 1, As[1], 1, tid); }, {});
    PHASE8(As[0], Bs[0], 2, false,
           { if (pf2) stage_half(Bw, brow0, lda, kt0 + 2, Bs[0], 0, tid); }, {});
    PHASE8(As[0], Bs[0], 3, false,
           { if (pf2) stage_half(Bw, brow0, lda, kt0 + 2, Bs[0], 1, tid); },
           { if (pf2) { asm volatile("s_waitcnt vmcnt(4)" ::: "memory"); }
             else     { asm volatile("s_waitcnt vmcnt(0)" ::: "memory"); } });
    // ---- K-tile kt1 (As[1]/Bs[1]) : phases 5-8 ----
    PHASE8(As[1], Bs[1], 0, true,
           { if (pf2) stage_half(A, arow0, lda, kt0 + 2, As[0], 0, tid); }, {});
    PHASE8(As[1], Bs[1], 1, false,
           { if (pf2) stage_half(A, arow0, lda, kt0 + 2, As[0], 1, tid); }, {});
    PHASE8(As[1], Bs[1], 2, false,
           { if (pf3) stage_half(Bw, brow0, lda, kt0 + 3, Bs[1], 0, tid); }, {});
    PHASE8(As[1], Bs[1], 3, false,
           { if (pf3) stage_half(Bw, brow0, lda, kt0 + 3, Bs[1], 1, tid); },
           { if (pf3) { asm volatile("s_waitcnt vmcnt(4)" ::: "memory"); } });
  }

  // ---- epilogue ----
  const int row_base = blockIdx.x * 256 + wm * 128;
  if (EPI == 2) {
    const int cg0 = blockIdx.y * 128 + wn * 32;
#pragma unroll
    for (int mt = 0; mt < 8; ++mt) {
      const int r0 = row_base + mt * 16 + ((lane >> 4) << 2);
#pragma unroll
      for (int pr = 0; pr < 2; ++pr) {
        const int col = cg0 + pr * 16 + rsel;
#pragma unroll
        for (int j = 0; j < 4; ++j) {
          const int row = r0 + j;
          if (row < Mvalid) {
            float u1 = acc[mt][pr * 2][j];
            float u2 = acc[mt][pr * 2 + 1][j];
            float sv = u1 / (1.0f + expf(-u1));
            ((unsigned short*)C)[(size_t)row * ldc + col] = f2b(sv * u2);
          }
        }
      }
    }
  } else {
    const int col_base = blockIdx.y * 256 + wn * 64;
#pragma unroll
    for (int mt = 0; mt < 8; ++mt) {
#pragma unroll
      for (int nt = 0; nt < 4; ++nt) {
        const int col = col_base + nt * 16 + rsel;
        const int r0 = row_base + mt * 16 + ((lane >> 4) << 2);
#pragma unroll
        for (int j = 0; j < 4; ++j) {
          const int row = r0 + j;
          if (row < Mvalid)
            ((unsigned short*)C)[(size_t)row * ldc + col] = f2b(acc[mt][nt][j]);
        }
      }
    }
  }
}

// ---------------- host ----------------
extern "C" void kernel_launch(void* const* d_in, const int* in_sizes, int n_in,
                              void* d_out, int out_size, void* d_ws, size_t ws_size,
                              hipStream_t stream) {
  const float* noisy = (const float*)d_in[0];
  const float* nlvl = (const float*)d_in[1];
  const float* actions = (const float*)d_in[2];
  const void* indep = d_in[3];
  const void* amask = d_in[4];
  const float* W_in = (const float*)d_in[5];
  const float* noise_w1 = (const float*)d_in[6];
  const float* noise_b1 = (const float*)d_in[7];
  const float* noise_w2 = (const float*)d_in[8];
  const float* noise_b2 = (const float*)d_in[9];
  const float* base_emb = (const float*)d_in[10];
  const float* action_w = (const float*)d_in[11];
  const float* action_b = (const float*)d_in[12];
  const float* registers = (const float*)d_in[13];
  const float* ln1_w = (const float*)d_in[14];
  const float* Wqkv_s = (const float*)d_in[15];
  const float* Wo_s = (const float*)d_in[16];
  const float* lnt_w = (const float*)d_in[17];
  const float* Wqkv_t = (const float*)d_in[18];
  const float* Wo_t = (const float*)d_in[19];
  const float* ln2_w = (const float*)d_in[20];
  const float* W1 = (const float*)d_in[21];
  const float* W2 = (const float*)d_in[22];
  const float* W3 = (const float*)d_in[23];
  const float* final_w = (const float*)d_in[24];
  const float* W_out = (const float*)d_in[25];
  const float* b_out = (const float*)d_in[26];

  char* p = (char*)d_ws;
  auto alloc = [&](size_t bytes) {
    char* r = p;
    p += (bytes + 255) & ~(size_t)255;
    return r;
  };
  float* X = (float*)alloc((size_t)NTOKP * 1024 * 4);
  unsigned short* HB = (unsigned short*)alloc((size_t)NTOKP * 1024 * 2);
  unsigned short* AO = (unsigned short*)alloc((size_t)NTOKP * 1024 * 2);
  char* SCR = alloc((size_t)NTOKP * 4096 * 2);
  unsigned short* QKV = (unsigned short*)SCR;
  unsigned short* G = (unsigned short*)SCR;
  unsigned short* NLB = (unsigned short*)SCR;
  float* NZ = (float*)alloc(32 * 1024 * 4);
  float* H1 = (float*)alloc(32 * 1024 * 4);
  float2* RSP = (float2*)alloc(262 * 32 * 8);
  float2* RTM = (float2*)alloc(16 * 32 * 8);
  unsigned short* WINT = (unsigned short*)alloc((size_t)1024 * 768 * 2);
  unsigned short* WQKVS = (unsigned short*)alloc((size_t)8 * 3072 * 1024 * 2);
  unsigned short* WOS = (unsigned short*)alloc((size_t)8 * 1024 * 1024 * 2);
  unsigned short* WQKVT = (unsigned short*)alloc((size_t)2 * 3072 * 1024 * 2);
  unsigned short* WOT = (unsigned short*)alloc((size_t)2 * 1024 * 1024 * 2);
  unsigned short* W12T = (unsigned short*)alloc((size_t)8 * 8192 * 1024 * 2);
  unsigned short* W3T = (unsigned short*)alloc((size_t)8 * 1024 * 4096 * 2);
  unsigned short* WOUTT = (unsigned short*)alloc((size_t)768 * 1024 * 2);

  auto tr = [&](const float* in, unsigned short* out, int K, int N, int ostride, int mode) {
    dim3 g(K / 32, N / 32);
    transpose_w<<<g, 256, 0, stream>>>(in, out, K, N, ostride, mode);
  };
  tr(W_in, WINT, 768, 1024, 768, 0);
  for (int i = 0; i < 8; ++i) {
    tr(Wqkv_s + (size_t)i * 1024 * 3072, WQKVS + (size_t)i * 3072 * 1024, 1024, 3072, 1024, 0);
    tr(Wo_s + (size_t)i * 1024 * 1024, WOS + (size_t)i * 1024 * 1024, 1024, 1024, 1024, 0);
    tr(W1 + (size_t)i * 1024 * 4096, W12T + (size_t)i * 8192 * 1024, 1024, 4096, 1024, 1);
    tr(W2 + (size_t)i * 1024 * 4096, W12T + (size_t)i * 8192 * 1024, 1024, 4096, 1024, 2);
    tr(W3 + (size_t)i * 4096 * 1024, W3T + (size_t)i * 1024 * 4096, 4096, 1024, 4096, 0);
  }
  for (int s = 0; s < 2; ++s) { // temporal weights only used by layers 0 and 4
    int i = s * 4;
    tr(Wqkv_t + (size_t)i * 1024 * 3072, WQKVT + (size_t)s * 3072 * 1024, 1024, 3072, 1024, 0);
    tr(Wo_t + (size_t)i * 1024 * 1024, WOT + (size_t)s * 1024 * 1024, 1024, 1024, 1024, 0);
  }
  tr(W_out, WOUTT, 1024, 768, 1024, 0);

  build_rope<<<33, 256, 0, stream>>>(RSP, 262);
  build_rope<<<2, 256, 0, stream>>>(RTM, 16);
  conv_f2b<<<6144, 256, 0, stream>>>(noisy, NLB, (NLAT * 768) / 4);
  noise_h1<<<128, 256, 0, stream>>>(nlvl, noise_w1, noise_b1, noise_b2, H1, NZ);
  noise_mm<<<128, 256, 0, stream>>>(H1, noise_w2, NZ);
  embed_special<<<32, 1024, 0, stream>>>(X, registers, NZ, base_emb, actions, action_w, action_b, amask);
  {
    dim3 g(64, 8);
    gemm_k<5><<<g, 256, 0, stream>>>(NLB, WINT, X, nullptr, NLAT, 768, 768, 1024);
  }

  for (int i = 0; i < 8; ++i) {
    // --- spatial attention ---
    rms_k<false><<<NTOK, 256, 0, stream>>>(X, ln1_w + i * 1024, HB);
    {
      dim3 g(66, 24);
      gemm_k<0><<<g, 256, 0, stream>>>(HB, WQKVS + (size_t)i * 3072 * 1024, QKV, nullptr, NTOK, 1024, 1024, 3072);
    }
    attn_spatial<<<512, 256, 0, stream>>>(QKV, AO, RSP);
    {
      dim3 g(66, 8);
      gemm_k<1><<<g, 256, 0, stream>>>(AO, WOS + (size_t)i * 1024 * 1024, X, nullptr, NTOK, 1024, 1024, 1024);
    }
    // --- temporal attention (layers 0,4) ---
    if ((i & 3) == 0) {
      const int s = i >> 2;
      rms_k<false><<<NTOK, 256, 0, stream>>>(X, lnt_w + i * 1024, HB);
      {
        dim3 g(66, 24);
        gemm_k<0><<<g, 256, 0, stream>>>(HB, WQKVT + (size_t)s * 3072 * 1024, QKV, nullptr, NTOK, 1024, 1024, 3072);
      }
      attn_temporal<<<2096, 256, 0, stream>>>(QKV, AO, RTM, indep);
      {
        dim3 g(66, 8);
        gemm_k<1><<<g, 256, 0, stream>>>(AO, WOT + (size_t)s * 1024 * 1024, X, nullptr, NTOK, 1024, 1024, 1024);
      }
    }
    // --- MLP ---
    rms_k<false><<<NTOK, 256, 0, stream>>>(X, ln2_w + i * 1024, HB);
    {
      dim3 g(33, 32); // SwiGLU on the 8-phase 256^2 kernel (W12T: 8192 rows)
      gemm8p_k<2><<<g, 512, 0, stream>>>(HB, W12T + (size_t)i * 8192 * 1024, G, NTOK, 1024, 1024, 4096);
    }
    {
      dim3 g(66, 8);
      gemm_k<1><<<g, 256, 0, stream>>>(G, W3T + (size_t)i * 1024 * 4096, X, nullptr, NTOK, 4096, 4096, 1024);
    }
  }

  // final norm over latent tokens + output projection (+bias) straight to d_out
  rms_k<true><<<NLAT, 256, 0, stream>>>(X, final_w, HB);
  {
    dim3 g(64, 6);
    gemm_k<3><<<g, 256, 0, stream>>>(HB, WOUTT, d_out, b_out, NLAT, 1024, 1024, 768);
  }
}

// Round 15
// 5886.588 us; speedup vs baseline: 1.0211x; 1.0211x over previous
//
#include <hip/hip_runtime.h>
#include <cstdint>
#include <cstddef>

#define DEV __device__ __forceinline__

typedef __attribute__((ext_vector_type(8))) __bf16 bf16x8;
typedef __attribute__((ext_vector_type(4))) float f32x4;

// ---------------- problem constants ----------------
// B=2 T=16 L=256 IN=768 D=1024 H=16 HD=64 S=262 P=6 HID=4096 DEPTH=8
#define NTOK   8384            // B*T*S
#define NTOKP  8448            // padded to 66*128
#define NLAT   8192            // B*T*L

DEV float b2f(unsigned short u) {
  unsigned int x = ((unsigned int)u) << 16;
  return __builtin_bit_cast(float, x);
}
DEV unsigned short f2b(float f) {
  unsigned int x = __builtin_bit_cast(unsigned int, f);
  x += 0x7fffu + ((x >> 16) & 1u);
  return (unsigned short)(x >> 16);
}
DEV float wred_sum(float v) {
#pragma unroll
  for (int o = 32; o; o >>= 1) v += __shfl_xor(v, o);
  return v;
}
// bool inputs may arrive as uint8 or int32 ("integer -> const int*").
DEV bool mask_or(const void* p, int i) {
  return ((const unsigned char*)p)[i] != 0 || ((const int*)p)[i] != 0;
}
DEV bool mask_and(const void* p, int i) {
  return ((const unsigned char*)p)[i] != 0 && ((const int*)p)[i] != 0;
}

// ---------------- elementwise / setup kernels ----------------

__global__ void conv_f2b(const float* __restrict__ in, unsigned short* __restrict__ out, int n4) {
  int i = blockIdx.x * 256 + threadIdx.x;
  if (i < n4) {
    float4 v = ((const float4*)in)[i];
    ushort4 o;
    o.x = f2b(v.x); o.y = f2b(v.y); o.z = f2b(v.z); o.w = f2b(v.w);
    ((ushort4*)out)[i] = o;
  }
}

__global__ void build_rope(float2* __restrict__ out, int npos) {
  int idx = blockIdx.x * 256 + threadIdx.x;
  if (idx >= npos * 32) return;
  int pos = idx >> 5, i = idx & 31;
  float inv = powf(1000.0f, -(float)(2 * i) * (1.0f / 64.0f));
  float ang = (float)pos * inv;
  float sv, cv;
  sincosf(ang, &sv, &cv);
  out[idx] = make_float2(cv, sv);
}

// fp32 [K][N] -> bf16 [row(n)][K] ; MODE 0: row=n
// MODE 1 (W1 16-col interleave): row = ((n>>4)<<5) | (n&15)
// MODE 2 (W2):                    row = (((n>>4)<<5) + 16) | (n&15)
__global__ __launch_bounds__(256) void transpose_w(const float* __restrict__ in,
                                                   unsigned short* __restrict__ out,
                                                   int K, int N, int ostride, int mode) {
  __shared__ float tile[32][33];
  int kb = blockIdx.x * 32, nb = blockIdx.y * 32;
  int tx = threadIdx.x & 31, ty = threadIdx.x >> 5; // 32x8
#pragma unroll
  for (int i = 0; i < 32; i += 8)
    tile[ty + i][tx] = in[(size_t)(kb + ty + i) * N + (nb + tx)];
  __syncthreads();
#pragma unroll
  for (int i = 0; i < 32; i += 8) {
    int n = nb + ty + i;
    int row = n;
    if (mode == 1) row = ((n >> 4) << 5) | (n & 15);
    else if (mode == 2) row = (((n >> 4) << 5) + 16) | (n & 15);
    out[(size_t)row * ostride + (kb + tx)] = f2b(tile[tx][ty + i]);
  }
}

// h1 = silu(nl*w1+b1) ; nz = b2 (init for noise_mm accumulate). 128 blocks x 256.
__global__ __launch_bounds__(256) void noise_h1(const float* __restrict__ nlvl,
                                                const float* __restrict__ w1,
                                                const float* __restrict__ b1,
                                                const float* __restrict__ b2,
                                                float* __restrict__ h1,
                                                float* __restrict__ nz) {
  int i = blockIdx.x * 256 + threadIdx.x; // 32*1024
  int bt = i >> 10, d = i & 1023;
  float v = nlvl[bt] * w1[d] + b1[d];
  h1[i] = v / (1.0f + expf(-v));
  nz[i] = b2[d];
}

// nz += h1[32,1024] @ w2[1024,1024]
__global__ __launch_bounds__(256) void noise_mm(const float* __restrict__ h1,
                                                const float* __restrict__ w2,
                                                float* __restrict__ nz) {
  __shared__ float hs[32][128];
  int kc = blockIdx.x >> 4, dpg = blockIdx.x & 15;
  int tid = threadIdx.x;
  int k0 = kc * 128;
  for (int idx = tid; idx < 32 * 128; idx += 256) {
    int bt = idx >> 7, k = idx & 127;
    hs[bt][k] = h1[bt * 1024 + k0 + k];
  }
  __syncthreads();
  int dp = dpg * 64 + (tid & 63);
  int bt0 = (tid >> 6) * 8;
  float acc[8] = {};
  for (int k = 0; k < 128; ++k) {
    float w = w2[(size_t)(k0 + k) * 1024 + dp];
#pragma unroll
    for (int j = 0; j < 8; ++j) acc[j] += hs[bt0 + j][k] * w;
  }
#pragma unroll
  for (int j = 0; j < 8; ++j) atomicAdd(&nz[(bt0 + j) * 1024 + dp], acc[j]);
}

// writes x rows 0..5 per frame (registers, noise, action)
__global__ void embed_special(float* __restrict__ x, const float* __restrict__ regs,
                              const float* __restrict__ nz, const float* __restrict__ base_emb,
                              const float* __restrict__ actions, const float* __restrict__ action_w,
                              const float* __restrict__ action_b,
                              const void* __restrict__ amask) {
  int bt = blockIdx.x, d = threadIdx.x; // 32 blocks x 1024 threads
  float* xr = x + (size_t)bt * 262 * 1024;
#pragma unroll
  for (int r = 0; r < 4; ++r) xr[r * 1024 + d] = regs[r * 1024 + d];
  xr[4 * 1024 + d] = nz[(size_t)bt * 1024 + d];
  float a = base_emb[d];
  if (mask_or(amask, bt)) {
    float s = action_b[d];
#pragma unroll
    for (int i = 0; i < 6; ++i) s += actions[bt * 6 + i] * action_w[i * 1024 + d];
    a += s;
  }
  xr[5 * 1024 + d] = a;
}

// RMS over D=1024 with weight; REMAP compacts latent tokens (for final norm)
template <bool REMAP>
__global__ __launch_bounds__(256) void rms_k(const float* __restrict__ x,
                                             const float* __restrict__ w,
                                             unsigned short* __restrict__ out) {
  int m = blockIdx.x, tid = threadIdx.x;
  size_t src = REMAP ? ((size_t)(m >> 8) * 262 + 6 + (m & 255)) : (size_t)m;
  float4 v = ((const float4*)(x + src * 1024))[tid];
  float ss = v.x * v.x + v.y * v.y + v.z * v.z + v.w * v.w;
  ss = wred_sum(ss);
  __shared__ float sred[4];
  if ((tid & 63) == 0) sred[tid >> 6] = ss;
  __syncthreads();
  float tot = sred[0] + sred[1] + sred[2] + sred[3];
  float sc = rsqrtf(tot * (1.0f / 1024.0f) + 1e-6f);
  float4 wv = ((const float4*)w)[tid];
  ushort4 o;
  o.x = f2b(v.x * sc * wv.x); o.y = f2b(v.y * sc * wv.y);
  o.z = f2b(v.z * sc * wv.z); o.w = f2b(v.w * sc * wv.w);
  ((ushort4*)(out + (size_t)m * 1024))[tid] = o;
}

// ---------------- attention ----------------
// spatial (MFMA): one block per (b,t,h); 4 waves; each wave owns 16-row q-chunks.
// QKV is bf16; per-head RMS + RoPE fused here (K during staging, Q at frag load).
// K staged [272][72] bf16, V^T staged [64][296] bf16, P per-wave [16][296] bf16.
// mask: rows 4,5 attend only self; all others attend all 262.
#define KSTR 72
#define VSTR 296
__global__ __launch_bounds__(256) void attn_spatial(const unsigned short* __restrict__ qkv,
                                                    unsigned short* __restrict__ o,
                                                    const float2* __restrict__ rope) {
  __shared__ unsigned short Ks[272 * KSTR];
  __shared__ unsigned short Vt[64 * VSTR];
  __shared__ unsigned short Ps[4][16 * VSTR];
  const int h = blockIdx.x & 15;
  const int bt = blockIdx.x >> 4;
  const int tid = threadIdx.x, wave = tid >> 6, lane = tid & 63;
  const size_t tb = (size_t)bt * 262;

  // ---- stage K (rms+rope, row-major) and V (transposed) ----
  {
    const int d = lane;
#pragma unroll 1
    for (int pss = 0; pss < 17; ++pss) {
      const int t0 = (pss * 4 + wave) * 4; // 4 tokens per wave per pass
      ushort4 vp;
      unsigned short* vpp = (unsigned short*)&vp;
#pragma unroll
      for (int j = 0; j < 4; ++j) {
        const int t = t0 + j;
        float kv = 0.f, vv = 0.f;
        if (t < 262) {
          const size_t rb = (tb + t) * 3072 + h * 64 + d;
          kv = b2f(qkv[rb + 1024]);
          vv = b2f(qkv[rb + 2048]);
        }
        // per-(token,head) rms over 64 dims
        float ss = wred_sum(kv * kv);
        kv *= rsqrtf(ss * (1.0f / 64.0f) + 1e-6f);
        // rope (position = spatial index t)
        float partner = __shfl_xor(kv, 1);
        const int tc = t < 262 ? t : 261;
        float2 cs = rope[tc * 32 + (d >> 1)];
        kv = ((d & 1) == 0) ? (kv * cs.x - partner * cs.y)
                            : (partner * cs.y + kv * cs.x);
        Ks[t * KSTR + d] = f2b(kv);
        vpp[j] = f2b(vv);
      }
      *(ushort4*)(&Vt[d * VSTR + t0]) = vp;
    }
    // zero pads: Vt cols [272,296), Ps cols [262,296) for all 4 wave buffers
    for (int idx = tid; idx < 64 * 24; idx += 256) {
      Vt[(idx / 24) * VSTR + 272 + (idx % 24)] = 0;
    }
    for (int idx = tid; idx < 4 * 16 * 34; idx += 256) {
      int w = idx / (16 * 34), r = (idx / 34) & 15, c = idx % 34;
      Ps[w][r * VSTR + 262 + c] = 0;
    }
  }
  __syncthreads();

  unsigned short* Pw = &Ps[wave][0];
  const int kcol = lane & 15;
  const int g8 = (lane >> 4) << 3;   // 8-element k-slice offset within 32
  const int g4 = g8 >> 1;            // rope pair base within 16
  const int rq = (lane >> 4) << 2;   // accumulator row base

#pragma unroll 1
  for (int qc = wave; qc < 17; qc += 4) {
    const int q0 = qc * 16;
    // ---- Q A-frags from global bf16, fused rms (4-lane reduce) + in-lane rope ----
    const int qrow = q0 + kcol;
    const int grow = qrow < 262 ? qrow : 261;
    const unsigned short* qp = qkv + (tb + grow) * 3072 + h * 64 + g8;
    float qv[16];
    {
      ushort4 a = *(const ushort4*)qp, b = *(const ushort4*)(qp + 4);
      ushort4 c = *(const ushort4*)(qp + 32), e = *(const ushort4*)(qp + 36);
      qv[0] = b2f(a.x); qv[1] = b2f(a.y); qv[2] = b2f(a.z); qv[3] = b2f(a.w);
      qv[4] = b2f(b.x); qv[5] = b2f(b.y); qv[6] = b2f(b.z); qv[7] = b2f(b.w);
      qv[8] = b2f(c.x); qv[9] = b2f(c.y); qv[10] = b2f(c.z); qv[11] = b2f(c.w);
      qv[12] = b2f(e.x); qv[13] = b2f(e.y); qv[14] = b2f(e.z); qv[15] = b2f(e.w);
    }
    float ss = 0.f;
#pragma unroll
    for (int i = 0; i < 16; ++i) ss += qv[i] * qv[i];
    ss += __shfl_xor(ss, 16);
    ss += __shfl_xor(ss, 32);
    const float qsc = rsqrtf(ss * (1.0f / 64.0f) + 1e-6f);
    bf16x8 aq0, aq1;
    unsigned short* u0 = (unsigned short*)&aq0;
    unsigned short* u1 = (unsigned short*)&aq1;
#pragma unroll
    for (int i = 0; i < 4; ++i) {
      float2 cs0 = rope[grow * 32 + g4 + i];
      float a = qv[2 * i] * qsc, b = qv[2 * i + 1] * qsc;
      u0[2 * i] = f2b(a * cs0.x - b * cs0.y);
      u0[2 * i + 1] = f2b(a * cs0.y + b * cs0.x);
      float2 cs1 = rope[grow * 32 + 16 + g4 + i];
      float a1 = qv[8 + 2 * i] * qsc, b1 = qv[9 + 2 * i] * qsc;
      u1[2 * i] = f2b(a1 * cs1.x - b1 * cs1.y);
      u1[2 * i + 1] = f2b(a1 * cs1.y + b1 * cs1.x);
    }
    // ---- scores: 17 k-chunks x (2 MFMA over HD=64) ----
    f32x4 sc[17];
#pragma unroll
    for (int kc = 0; kc < 17; ++kc) {
      const unsigned short* kb = &Ks[(kc * 16 + kcol) * KSTR + g8];
      f32x4 z = {};
      z = __builtin_amdgcn_mfma_f32_16x16x32_bf16(aq0, *(const bf16x8*)kb, z, 0, 0, 0);
      sc[kc] = __builtin_amdgcn_mfma_f32_16x16x32_bf16(aq1, *(const bf16x8*)(kb + 32), z, 0, 0, 0);
    }
    // ---- mask + scale ----
#pragma unroll
    for (int kc = 0; kc < 17; ++kc) {
      const int k = kc * 16 + kcol;
#pragma unroll
      for (int j = 0; j < 4; ++j) {
        const int sq = q0 + rq + j;
        const bool valid = (k < 262) && ((sq != 4 && sq != 5) || (k == sq));
        sc[kc][j] = valid ? sc[kc][j] * 0.125f : -1e30f;
      }
    }
    // ---- softmax (per row over 272 cols; 16 lanes share same 4 rows) ----
    float sm[4];
#pragma unroll
    for (int j = 0; j < 4; ++j) {
      float m = -1e30f;
#pragma unroll
      for (int kc = 0; kc < 17; ++kc) m = fmaxf(m, sc[kc][j]);
#pragma unroll
      for (int off = 1; off < 16; off <<= 1) m = fmaxf(m, __shfl_xor(m, off));
      float s = 0.f;
#pragma unroll
      for (int kc = 0; kc < 17; ++kc) {
        float e = expf(sc[kc][j] - m);
        sc[kc][j] = e;
        s += e;
      }
#pragma unroll
      for (int off = 1; off < 16; off <<= 1) s += __shfl_xor(s, off);
      sm[j] = 1.0f / s;
    }
    // ---- write normalized P (bf16) to per-wave LDS ----
#pragma unroll
    for (int kc = 0; kc < 17; ++kc) {
      const int k = kc * 16 + kcol;
#pragma unroll
      for (int j = 0; j < 4; ++j)
        Pw[(rq + j) * VSTR + k] = f2b(sc[kc][j] * sm[j]);
    }
    // ---- PV: O[16][64] = P[16][288] * V[288][64] ----
    f32x4 oacc[4] = {};
#pragma unroll
    for (int tc = 0; tc < 9; ++tc) {
      const bf16x8 ap = *(const bf16x8*)(&Pw[kcol * VSTR + tc * 32 + g8]);
#pragma unroll
      for (int nt = 0; nt < 4; ++nt) {
        const bf16x8 bv = *(const bf16x8*)(&Vt[(nt * 16 + kcol) * VSTR + tc * 32 + g8]);
        oacc[nt] = __builtin_amdgcn_mfma_f32_16x16x32_bf16(ap, bv, oacc[nt], 0, 0, 0);
      }
    }
    // ---- output ----
#pragma unroll
    for (int nt = 0; nt < 4; ++nt) {
#pragma unroll
      for (int j = 0; j < 4; ++j) {
        const int sq = q0 + rq + j;
        if (sq < 262)
          o[(tb + sq) * 1024 + h * 64 + nt * 16 + kcol] = f2b(oacc[nt][j]);
      }
    }
  }
}

// temporal: one wave per (b,s,h); per-t rms+rope fused; strict-causal over T=16;
// s<6 or indep -> zeros
__global__ __launch_bounds__(256) void attn_temporal(const unsigned short* __restrict__ qkv,
                                                     unsigned short* __restrict__ o,
                                                     const float2* __restrict__ rope,
                                                     const void* __restrict__ indep) {
  int gw = blockIdx.x * 4 + (threadIdx.x >> 6);
  int lane = threadIdx.x & 63;
  if (gw >= NTOK) return;
  int h = gw & 15;
  int s = (gw >> 4) % 262;
  int b = (gw >> 4) / 262;
  bool dead = (s < 6) || mask_and(indep, b);
  float q[16], kk[16], vv[16], out[16];
#pragma unroll
  for (int t = 0; t < 16; ++t) {
    out[t] = 0.f;
    if (!dead) {
      size_t off = ((size_t)((b * 16 + t) * 262 + s)) * 3072 + h * 64 + lane;
      q[t] = b2f(qkv[off]);
      kk[t] = b2f(qkv[off + 1024]);
      vv[t] = b2f(qkv[off + 2048]);
    }
  }
  if (!dead) {
    // per-t rms + rope (position = t)
#pragma unroll
    for (int t = 0; t < 16; ++t) {
      float sq_ = wred_sum(q[t] * q[t]);
      float qv = q[t] * rsqrtf(sq_ * (1.0f / 64.0f) + 1e-6f);
      float sk_ = wred_sum(kk[t] * kk[t]);
      float kv = kk[t] * rsqrtf(sk_ * (1.0f / 64.0f) + 1e-6f);
      float2 cs = rope[t * 32 + (lane >> 1)];
      float qp = __shfl_xor(qv, 1);
      float kp = __shfl_xor(kv, 1);
      q[t] = ((lane & 1) == 0) ? (qv * cs.x - qp * cs.y) : (qp * cs.y + qv * cs.x);
      kk[t] = ((lane & 1) == 0) ? (kv * cs.x - kp * cs.y) : (kp * cs.y + kv * cs.x);
    }
#pragma unroll
    for (int t = 1; t < 16; ++t) {
      float m = -1e30f, l = 0.f, acc = 0.f;
#pragma unroll
      for (int j = 0; j < t; ++j) {
        float pr = q[t] * kk[j];
#pragma unroll
        for (int o2 = 32; o2; o2 >>= 1) pr += __shfl_xor(pr, o2);
        pr *= 0.125f;
        float mn = fmaxf(m, pr);
        float cor = expf(m - mn);
        float e = expf(pr - mn);
        l = l * cor + e;
        acc = acc * cor + e * vv[j];
        m = mn;
      }
      out[t] = acc / l;
    }
  }
#pragma unroll
  for (int t = 0; t < 16; ++t) {
    size_t off = ((size_t)((b * 16 + t) * 262 + s)) * 1024 + h * 64 + lane;
    o[off] = f2b(out[t]);
  }
}

// ---------------- GEMM 128x128 (round-4 structure: 2-buffer, __syncthreads) ----
// A: [Mpad][lda] bf16 ; Bw: [N][lda] bf16 ; epilogues by EPI:
// 0: bf16 C=acc                    1: f32 C += acc (residual)
// 2: swiglu (W12T 16-col interleave): nt pairs (2p,2p+1)=(u1,u2), coalesced bf16
// 3: f32 C = acc + aux[col]        5: f32 scatter to x rows (row>>8)*262+6+(row&255)
DEV void stage_tiles(const unsigned short* __restrict__ A, const unsigned short* __restrict__ Bw,
                     size_t arow0, size_t brow0, int lda, int k0,
                     unsigned short* As, unsigned short* Bs, int wave, int lane) {
  const int srow = lane >> 2;
  const int scol = (lane & 3) * 8;
#pragma unroll
  for (int c = 0; c < 2; ++c) {
    const int chunk = wave * 2 + c;
    unsigned short* ga = const_cast<unsigned short*>(A + (arow0 + chunk * 16 + srow) * lda + k0 + scol);
    unsigned short* gb = const_cast<unsigned short*>(Bw + (brow0 + chunk * 16 + srow) * lda + k0 + scol);
    __builtin_amdgcn_global_load_lds((__attribute__((address_space(1))) void*)ga,
                                     (__attribute__((address_space(3))) void*)(As + chunk * 512),
                                     16, 0, 0);
    __builtin_amdgcn_global_load_lds((__attribute__((address_space(1))) void*)gb,
                                     (__attribute__((address_space(3))) void*)(Bs + chunk * 512),
                                     16, 0, 0);
  }
}

template <int EPI>
__global__ __launch_bounds__(256) void gemm_k(const unsigned short* __restrict__ A,
                                              const unsigned short* __restrict__ Bw,
                                              void* __restrict__ C,
                                              const float* __restrict__ aux,
                                              int Mvalid, int K, int lda, int ldc) {
  __shared__ unsigned short As[2][128 * 32];
  __shared__ unsigned short Bs[2][128 * 32];
  const int tid = threadIdx.x;
  const int wave = tid >> 6, lane = tid & 63;
  const int wm = wave >> 1, wn = wave & 1;
  const size_t arow0 = (size_t)blockIdx.x * 128;
  const size_t brow0 = (size_t)blockIdx.y * 128;

  f32x4 acc[4][4] = {};
  const int KT = K >> 5;

  stage_tiles(A, Bw, arow0, brow0, lda, 0, As[0], Bs[0], wave, lane);
  __syncthreads();
  int buf = 0;
  for (int kt = 0; kt < KT; ++kt) {
    if (kt + 1 < KT)
      stage_tiles(A, Bw, arow0, brow0, lda, (kt + 1) << 5, As[buf ^ 1], Bs[buf ^ 1], wave, lane);
    const int kk = (lane >> 4) * 8;
    const int rsel = lane & 15;
    bf16x8 af[4], bfr[4];
#pragma unroll
    for (int mt = 0; mt < 4; ++mt)
      af[mt] = *reinterpret_cast<const bf16x8*>(&As[buf][(wm * 64 + mt * 16 + rsel) * 32 + kk]);
#pragma unroll
    for (int nt = 0; nt < 4; ++nt)
      bfr[nt] = *reinterpret_cast<const bf16x8*>(&Bs[buf][(wn * 64 + nt * 16 + rsel) * 32 + kk]);
#pragma unroll
    for (int mt = 0; mt < 4; ++mt) {
#pragma unroll
      for (int nt = 0; nt < 4; ++nt)
        acc[mt][nt] = __builtin_amdgcn_mfma_f32_16x16x32_bf16(af[mt], bfr[nt], acc[mt][nt], 0, 0, 0);
    }
    __syncthreads();
    buf ^= 1;
  }

  const int rsel = lane & 15;
  const int row_base = blockIdx.x * 128 + wm * 64;
  const int col_base = blockIdx.y * 128 + wn * 64;

  if (EPI == 2) {
    // W12T rows at 16-col interleave: nt=0,1 -> (u1,u2) cols cg0..+15; nt=2,3 -> +16
    const int cg0 = blockIdx.y * 64 + wn * 32;
#pragma unroll
    for (int mt = 0; mt < 4; ++mt) {
#pragma unroll
      for (int pr = 0; pr < 2; ++pr) {
        const int col = cg0 + pr * 16 + rsel;
        const int r0 = row_base + mt * 16 + ((lane >> 4) << 2);
#pragma unroll
        for (int j = 0; j < 4; ++j) {
          const int row = r0 + j;
          if (row < Mvalid) {
            float u1 = acc[mt][pr * 2][j];
            float u2 = acc[mt][pr * 2 + 1][j];
            float sv = u1 / (1.0f + expf(-u1));
            ((unsigned short*)C)[(size_t)row * ldc + col] = f2b(sv * u2);
          }
        }
      }
    }
    return;
  }

#pragma unroll
  for (int mt = 0; mt < 4; ++mt) {
#pragma unroll
    for (int nt = 0; nt < 4; ++nt) {
      const int col = col_base + nt * 16 + rsel;
      const int r0 = row_base + mt * 16 + ((lane >> 4) << 2);
#pragma unroll
      for (int j = 0; j < 4; ++j) {
        const int row = r0 + j;
        float v = acc[mt][nt][j];
        if (row < Mvalid) {
          if (EPI == 0) {
            ((unsigned short*)C)[(size_t)row * ldc + col] = f2b(v);
          } else if (EPI == 1) {
            float* p = (float*)C + (size_t)row * ldc + col;
            *p += v;
          } else if (EPI == 3) {
            ((float*)C)[(size_t)row * ldc + col] = v + aux[col];
          } else if (EPI == 5) {
            int xr = (row >> 8) * 262 + 6 + (row & 255);
            ((float*)C)[(size_t)xr * ldc + col] = v;
          }
        }
      }
    }
  }
}

// ---------------- host ----------------
extern "C" void kernel_launch(void* const* d_in, const int* in_sizes, int n_in,
                              void* d_out, int out_size, void* d_ws, size_t ws_size,
                              hipStream_t stream) {
  const float* noisy = (const float*)d_in[0];
  const float* nlvl = (const float*)d_in[1];
  const float* actions = (const float*)d_in[2];
  const void* indep = d_in[3];
  const void* amask = d_in[4];
  const float* W_in = (const float*)d_in[5];
  const float* noise_w1 = (const float*)d_in[6];
  const float* noise_b1 = (const float*)d_in[7];
  const float* noise_w2 = (const float*)d_in[8];
  const float* noise_b2 = (const float*)d_in[9];
  const float* base_emb = (const float*)d_in[10];
  const float* action_w = (const float*)d_in[11];
  const float* action_b = (const float*)d_in[12];
  const float* registers = (const float*)d_in[13];
  const float* ln1_w = (const float*)d_in[14];
  const float* Wqkv_s = (const float*)d_in[15];
  const float* Wo_s = (const float*)d_in[16];
  const float* lnt_w = (const float*)d_in[17];
  const float* Wqkv_t = (const float*)d_in[18];
  const float* Wo_t = (const float*)d_in[19];
  const float* ln2_w = (const float*)d_in[20];
  const float* W1 = (const float*)d_in[21];
  const float* W2 = (const float*)d_in[22];
  const float* W3 = (const float*)d_in[23];
  const float* final_w = (const float*)d_in[24];
  const float* W_out = (const float*)d_in[25];
  const float* b_out = (const float*)d_in[26];

  char* p = (char*)d_ws;
  auto alloc = [&](size_t bytes) {
    char* r = p;
    p += (bytes + 255) & ~(size_t)255;
    return r;
  };
  // activations
  float* X = (float*)alloc((size_t)NTOKP * 1024 * 4);
  unsigned short* HB = (unsigned short*)alloc((size_t)NTOKP * 1024 * 2);
  unsigned short* AO = (unsigned short*)alloc((size_t)NTOKP * 1024 * 2);
  // SCR: QKV bf16 (attn) / G bf16 (mlp) / NLB bf16 (pre-layers) alias
  char* SCR = alloc((size_t)NTOKP * 4096 * 2);
  unsigned short* QKV = (unsigned short*)SCR;
  unsigned short* G = (unsigned short*)SCR;
  unsigned short* NLB = (unsigned short*)SCR;
  float* NZ = (float*)alloc(32 * 1024 * 4);
  float* H1 = (float*)alloc(32 * 1024 * 4);
  float2* RSP = (float2*)alloc(262 * 32 * 8);
  float2* RTM = (float2*)alloc(16 * 32 * 8);
  // transposed bf16 weights [N][K]
  unsigned short* WINT = (unsigned short*)alloc((size_t)1024 * 768 * 2);
  unsigned short* WQKVS = (unsigned short*)alloc((size_t)8 * 3072 * 1024 * 2);
  unsigned short* WOS = (unsigned short*)alloc((size_t)8 * 1024 * 1024 * 2);
  unsigned short* WQKVT = (unsigned short*)alloc((size_t)2 * 3072 * 1024 * 2); // layers 0,4 only
  unsigned short* WOT = (unsigned short*)alloc((size_t)2 * 1024 * 1024 * 2);   // layers 0,4 only
  unsigned short* W12T = (unsigned short*)alloc((size_t)8 * 8192 * 1024 * 2);
  unsigned short* W3T = (unsigned short*)alloc((size_t)8 * 1024 * 4096 * 2);
  unsigned short* WOUTT = (unsigned short*)alloc((size_t)768 * 1024 * 2);

  auto tr = [&](const float* in, unsigned short* out, int K, int N, int ostride, int mode) {
    dim3 g(K / 32, N / 32);
    transpose_w<<<g, 256, 0, stream>>>(in, out, K, N, ostride, mode);
  };
  tr(W_in, WINT, 768, 1024, 768, 0);
  for (int i = 0; i < 8; ++i) {
    tr(Wqkv_s + (size_t)i * 1024 * 3072, WQKVS + (size_t)i * 3072 * 1024, 1024, 3072, 1024, 0);
    tr(Wo_s + (size_t)i * 1024 * 1024, WOS + (size_t)i * 1024 * 1024, 1024, 1024, 1024, 0);
    // W1/W2 interleaved at 16-column granularity into W12T (8192 rows, stride 1024)
    tr(W1 + (size_t)i * 1024 * 4096, W12T + (size_t)i * 8192 * 1024, 1024, 4096, 1024, 1);
    tr(W2 + (size_t)i * 1024 * 4096, W12T + (size_t)i * 8192 * 1024, 1024, 4096, 1024, 2);
    tr(W3 + (size_t)i * 4096 * 1024, W3T + (size_t)i * 1024 * 4096, 4096, 1024, 4096, 0);
  }
  for (int s = 0; s < 2; ++s) { // temporal weights only used by layers 0 and 4
    int i = s * 4;
    tr(Wqkv_t + (size_t)i * 1024 * 3072, WQKVT + (size_t)s * 3072 * 1024, 1024, 3072, 1024, 0);
    tr(Wo_t + (size_t)i * 1024 * 1024, WOT + (size_t)s * 1024 * 1024, 1024, 1024, 1024, 0);
  }
  tr(W_out, WOUTT, 1024, 768, 1024, 0);

  build_rope<<<33, 256, 0, stream>>>(RSP, 262);
  build_rope<<<2, 256, 0, stream>>>(RTM, 16);
  conv_f2b<<<6144, 256, 0, stream>>>(noisy, NLB, (NLAT * 768) / 4);
  noise_h1<<<128, 256, 0, stream>>>(nlvl, noise_w1, noise_b1, noise_b2, H1, NZ);
  noise_mm<<<128, 256, 0, stream>>>(H1, noise_w2, NZ);
  embed_special<<<32, 1024, 0, stream>>>(X, registers, NZ, base_emb, actions, action_w, action_b, amask);
  // noisy tokens -> x (scatter into rows 6..261 per frame)
  {
    dim3 g(64, 8);
    gemm_k<5><<<g, 256, 0, stream>>>(NLB, WINT, X, nullptr, NLAT, 768, 768, 1024);
  }

  for (int i = 0; i < 8; ++i) {
    // --- spatial attention ---
    rms_k<false><<<NTOK, 256, 0, stream>>>(X, ln1_w + i * 1024, HB);
    {
      dim3 g(66, 24);
      gemm_k<0><<<g, 256, 0, stream>>>(HB, WQKVS + (size_t)i * 3072 * 1024, QKV, nullptr, NTOK, 1024, 1024, 3072);
    }
    attn_spatial<<<512, 256, 0, stream>>>(QKV, AO, RSP);
    {
      dim3 g(66, 8);
      gemm_k<1><<<g, 256, 0, stream>>>(AO, WOS + (size_t)i * 1024 * 1024, X, nullptr, NTOK, 1024, 1024, 1024);
    }
    // --- temporal attention (layers 0,4) ---
    if ((i & 3) == 0) {
      const int s = i >> 2;
      rms_k<false><<<NTOK, 256, 0, stream>>>(X, lnt_w + i * 1024, HB);
      {
        dim3 g(66, 24);
        gemm_k<0><<<g, 256, 0, stream>>>(HB, WQKVT + (size_t)s * 3072 * 1024, QKV, nullptr, NTOK, 1024, 1024, 3072);
      }
      attn_temporal<<<2096, 256, 0, stream>>>(QKV, AO, RTM, indep);
      {
        dim3 g(66, 8);
        gemm_k<1><<<g, 256, 0, stream>>>(AO, WOT + (size_t)s * 1024 * 1024, X, nullptr, NTOK, 1024, 1024, 1024);
      }
    }
    // --- MLP ---
    rms_k<false><<<NTOK, 256, 0, stream>>>(X, ln2_w + i * 1024, HB);
    {
      dim3 g(66, 64);
      gemm_k<2><<<g, 256, 0, stream>>>(HB, W12T + (size_t)i * 8192 * 1024, G, nullptr, NTOK, 1024, 1024, 4096);
    }
    {
      dim3 g(66, 8);
      gemm_k<1><<<g, 256, 0, stream>>>(G, W3T + (size_t)i * 1024 * 4096, X, nullptr, NTOK, 4096, 4096, 1024);
    }
  }

  // final norm over latent tokens + output projection (+bias) straight to d_out
  rms_k<true><<<NLAT, 256, 0, stream>>>(X, final_w, HB);
  {
    dim3 g(64, 6);
    gemm_k<3><<<g, 256, 0, stream>>>(HB, WOUTT, d_out, b_out, NLAT, 1024, 1024, 768);
  }
}